// Round 7
// baseline (724.299 us; speedup 1.0000x reference)
//
#include <hip/hip_runtime.h>
#include <hip/hip_cooperative_groups.h>
#include <cstdint>
#include <cstddef>

namespace cg = cooperative_groups;

#define BB 8
#define NN 2048
#define DD 256
#define EE 16
#define HH 8
#define CAPC 256
#define BN (BB*NN)   // 16384
#define EB (EE*BB)   // 128
#define GRID 512

// ---------------- shared-memory phase structs ----------------
struct SMG { float wgS[DD*EE]; float lgp[4][64][17]; };                        // 33.8 KB
struct SMQ { float aS[DD][8]; float qpart[8][32][9]; float qS[32][8]; };       // 18.2 KB
struct SMS { unsigned long long m1s[16][32], m2s[16][32];
             int wp1[16][32], wp2[16][32], mcnt[16]; float r4[4]; };           // 12.3 KB
struct SML { float rS[DD][8]; float lp[4][64][9]; int tokS[64]; };             // 17.5 KB
struct SMX { float lS[CAPC][9]; float aS2[HH][CAPC]; float part[4][HH][64];
             int tokS[CAPC]; float red[16]; };                                 // 26.4 KB
struct SMO { float xaS[8][DD]; float op[8][32][9]; };                          // 17.2 KB
union SMU { SMG g; SMQ q; SMS s; SML l; SMX xa; SMO og; };                     // 33.8 KB max

// ================================================================ phase device functions
__device__ void dev_gating(SMG& sm, int blk, int tid,
    const float* __restrict__ x, const float* __restrict__ wg,
    int* __restrict__ idx1a, int* __restrict__ idx2a,
    float* __restrict__ g1a, float* __restrict__ g2a,
    float* __restrict__ raw_part, float* __restrict__ cnt_part)
{
  for (int t = tid; t < DD*EE; t += 256) sm.wgS[t] = wg[t];
  __syncthreads();
  int tk = tid & 63, kc = tid >> 6;
  int token0 = blk * 64;
  int token = token0 + tk;
  const float4* xr = (const float4*)(x + (size_t)token*DD + kc*64);
  const float4* wg4 = (const float4*)sm.wgS;
  float lg[16];
#pragma unroll
  for (int e = 0; e < 16; ++e) lg[e] = 0.f;
#pragma unroll
  for (int d4 = 0; d4 < 16; ++d4) {
    float4 xv = xr[d4];
    float xav[4] = {xv.x, xv.y, xv.z, xv.w};
#pragma unroll
    for (int dd = 0; dd < 4; ++dd) {
      int d = kc*64 + d4*4 + dd;
      float xc = xav[dd];
#pragma unroll
      for (int j = 0; j < 4; ++j) {
        float4 w = wg4[d*4 + j];
        lg[4*j+0] += xc*w.x; lg[4*j+1] += xc*w.y;
        lg[4*j+2] += xc*w.z; lg[4*j+3] += xc*w.w;
      }
    }
  }
#pragma unroll
  for (int e = 0; e < 16; ++e) sm.lgp[kc][tk][e] = lg[e];
  __syncthreads();
  if (tid < 64) {
    int lane = tid;
    float l[16];
#pragma unroll
    for (int e = 0; e < 16; ++e)
      l[e] = sm.lgp[0][lane][e] + sm.lgp[1][lane][e]
           + sm.lgp[2][lane][e] + sm.lgp[3][lane][e];
    float mx = l[0];
#pragma unroll
    for (int e = 1; e < 16; ++e) mx = fmaxf(mx, l[e]);
    float p[16]; float s = 0.f;
#pragma unroll
    for (int e = 0; e < 16; ++e) { p[e] = expf(l[e] - mx); s += p[e]; }
    int i1 = 0; float b1 = p[0];
#pragma unroll
    for (int e = 1; e < 16; ++e) { if (p[e] > b1) { b1 = p[e]; i1 = e; } }
    float b2 = (i1 == 0) ? 0.f : p[0]; int i2 = 0;
#pragma unroll
    for (int e = 1; e < 16; ++e) { float v = (e == i1) ? 0.f : p[e]; if (v > b2) { b2 = v; i2 = e; } }
    float inv = 1.f / s;
    float g1 = b1*inv, g2 = b2*inv;
    float den = g1 + g2 + 1e-9f;
    g1 /= den; g2 /= den;
    int tok = token0 + lane;
    idx1a[tok] = i1; idx2a[tok] = i2;
    g1a[tok] = g1;   g2a[tok] = g2;
#pragma unroll
    for (int e = 0; e < 16; ++e) {
      float v = p[e] * inv;
      v += __shfl_down(v, 32); v += __shfl_down(v, 16);
      v += __shfl_down(v, 8);  v += __shfl_down(v, 4);
      v += __shfl_down(v, 2);  v += __shfl_down(v, 1);
      unsigned long long mb = __ballot(i1 == e);
      if (lane == 0) {
        raw_part[blk*16 + e] = v;
        cnt_part[blk*16 + e] = (float)__popcll(mb);
      }
    }
  }
}

__device__ void dev_qr(SMQ& sm, int eh, int tid,
    const float* __restrict__ audio, const float* __restrict__ Wq,
    const float* __restrict__ Wkv, float* __restrict__ rws)
{
  int e = eh >> 3, h = eh & 7;
  for (int i = tid; i < 2048; i += 256) { int b = i >> 8, k = i & 255; sm.aS[k][b] = audio[b*DD + k]; }
  __syncthreads();
  int j = tid & 31, kg = tid >> 5;
  const float* wq = Wq + (size_t)e*DD*DD + h*32 + j;
  float acc[8] = {0,0,0,0,0,0,0,0};
#pragma unroll
  for (int i = 0; i < 32; ++i) {
    int k = kg*32 + i;
    float w = wq[(size_t)k*DD];
    float4 a0 = *(const float4*)&sm.aS[k][0];
    float4 a1 = *(const float4*)&sm.aS[k][4];
    acc[0]+=w*a0.x; acc[1]+=w*a0.y; acc[2]+=w*a0.z; acc[3]+=w*a0.w;
    acc[4]+=w*a1.x; acc[5]+=w*a1.y; acc[6]+=w*a1.z; acc[7]+=w*a1.w;
  }
#pragma unroll
  for (int b = 0; b < 8; ++b) sm.qpart[kg][j][b] = acc[b];
  __syncthreads();
  {
    int jj = tid >> 3, b = tid & 7;
    float s = 0.f;
#pragma unroll
    for (int g = 0; g < 8; ++g) s += sm.qpart[g][jj][b];
    sm.qS[jj][b] = s;
  }
  __syncthreads();
  // r[b][d] = sum_j Wk[e][d][h*32+j] * q[j][b]; thread = d, Wk row read from global
  int d = tid;
  const float4* wk4 = (const float4*)(Wkv + (size_t)e*(DD*2*DD) + (size_t)d*(2*DD) + h*32);
  float racc[8] = {0,0,0,0,0,0,0,0};
#pragma unroll
  for (int j4 = 0; j4 < 8; ++j4) {
    float4 w4 = wk4[j4];
    float wa[4] = {w4.x, w4.y, w4.z, w4.w};
#pragma unroll
    for (int c = 0; c < 4; ++c) {
      int jj = j4*4 + c;
      float w = wa[c];
      float4 q0 = *(const float4*)&sm.qS[jj][0];
      float4 q1 = *(const float4*)&sm.qS[jj][4];
      racc[0]+=w*q0.x; racc[1]+=w*q0.y; racc[2]+=w*q0.z; racc[3]+=w*q0.w;
      racc[4]+=w*q1.x; racc[5]+=w*q1.y; racc[6]+=w*q1.z; racc[7]+=w*q1.w;
    }
  }
#pragma unroll
  for (int b = 0; b < 8; ++b)
    rws[((size_t)(e*8 + b))*2048 + d*8 + h] = racc[b];
}

__device__ void dev_scan(SMS& sm, int b, int tid,
    const int* __restrict__ idx1a, const int* __restrict__ idx2a,
    float* __restrict__ g1a, float* __restrict__ g2a, int* __restrict__ slot_token)
{
  int wave = tid >> 6, lane = tid & 63;
  for (int i = tid; i < 16*CAPC; i += 256) {
    int e = i >> 8, s = i & 255;
    slot_token[(e*BB + b)*CAPC + s] = -1;
  }
  for (int w = wave; w < 32; w += 4) {
    int token = b*NN + w*64 + lane;
    int i1 = idx1a[token], i2 = idx2a[token];
#pragma unroll
    for (int e = 0; e < 16; ++e) {
      unsigned long long ma = __ballot(i1 == e);
      unsigned long long mb = __ballot(i2 == e);
      if (lane == 0) { sm.m1s[e][w] = ma; sm.m2s[e][w] = mb; }
    }
  }
  __syncthreads();
  if (tid < 16) {
    int run = 0;
    for (int w = 0; w < 32; ++w) { sm.wp1[tid][w] = run; run += (int)__popcll(sm.m1s[tid][w]); }
    sm.mcnt[tid] = run < CAPC ? run : CAPC;
  } else if (tid < 32) {
    int e2 = tid - 16; int run = 0;
    for (int w = 0; w < 32; ++w) { sm.wp2[e2][w] = run; run += (int)__popcll(sm.m2s[e2][w]); }
  }
  __syncthreads();
  for (int w = wave; w < 32; w += 4) {
    int token = b*NN + w*64 + lane;
    int i1 = idx1a[token], i2 = idx2a[token];
    unsigned long long lt = (1ull << lane) - 1ull;
    int pos1 = sm.wp1[i1][w] + (int)__popcll(sm.m1s[i1][w] & lt);
    float g1 = g1a[token];
    bool k1 = pos1 < CAPC;
    g1a[token] = k1 ? g1 : 0.f;
    if (k1) slot_token[(i1*BB + b)*CAPC + pos1] = token;
    int pos2 = sm.mcnt[i2] + sm.wp2[i2][w] + (int)__popcll(sm.m2s[i2][w] & lt);
    float g2 = g2a[token];
    bool k2 = pos2 < CAPC;
    g2a[token] = k2 ? g2 : 0.f;
    if (k2 && g2 > 0.f) slot_token[(i2*BB + b)*CAPC + pos2] = token;
  }
}

__device__ void dev_loss(SMS& sm, int tid,
    const float* __restrict__ raw_part, const float* __restrict__ cnt_part,
    float* __restrict__ out_loss)
{
  float v = 0.f;
  if (tid < 128) {
    int bb = tid >> 4, e = tid & 15;
    float rs = 0.f, cs = 0.f;
#pragma unroll 4
    for (int k = 0; k < 32; ++k) {
      rs += raw_part[(bb*32 + k)*16 + e];
      cs += cnt_part[(bb*32 + k)*16 + e];
    }
    v = (rs * (1.f/(float)NN)) * (cs * (1.f/(float)NN));
  }
  v += __shfl_down(v, 32); v += __shfl_down(v, 16); v += __shfl_down(v, 8);
  v += __shfl_down(v, 4);  v += __shfl_down(v, 2);  v += __shfl_down(v, 1);
  if ((tid & 63) == 0) sm.r4[tid >> 6] = v;
  __syncthreads();
  if (tid == 0)
    out_loss[0] = (sm.r4[0]+sm.r4[1]+sm.r4[2]+sm.r4[3])
                * ((float)(EE*EE) / (float)(BB*EE)) * 0.01f;
}

__device__ void dev_lslot(SML& sm, int eb, int sc, int tid,
    const float* __restrict__ x, const float* __restrict__ rws,
    const int* __restrict__ slot_token, float* __restrict__ lslot)
{
  {
    const float4* rin = (const float4*)(rws + (size_t)eb*2048);
    float4* rS4 = (float4*)sm.rS;
    rS4[tid] = rin[tid]; rS4[tid+256] = rin[tid+256];
  }
  if (tid < 64) sm.tokS[tid] = slot_token[eb*CAPC + sc*64 + tid];
  __syncthreads();
  int s = tid >> 2, q = tid & 3;
  int token = sm.tokS[s];
  float l[8] = {0,0,0,0,0,0,0,0};
  if (token >= 0) {
    const float4* xr = (const float4*)(x + (size_t)token*DD + q*64);
#pragma unroll
    for (int i = 0; i < 16; ++i) {
      float4 xv = xr[i];
      float xav[4] = {xv.x, xv.y, xv.z, xv.w};
#pragma unroll
      for (int dd = 0; dd < 4; ++dd) {
        int d = q*64 + i*4 + dd;
        float4 r0 = *(const float4*)&sm.rS[d][0];
        float4 r1 = *(const float4*)&sm.rS[d][4];
        float xc = xav[dd];
        l[0]+=xc*r0.x; l[1]+=xc*r0.y; l[2]+=xc*r0.z; l[3]+=xc*r0.w;
        l[4]+=xc*r1.x; l[5]+=xc*r1.y; l[6]+=xc*r1.z; l[7]+=xc*r1.w;
      }
    }
  }
#pragma unroll
  for (int h = 0; h < 8; ++h) sm.lp[q][s][h] = l[h];
  __syncthreads();
#pragma unroll
  for (int r = 0; r < 2; ++r) {
    int o = tid*2 + r;
    int ss = o >> 3, h = o & 7;
    float v = (sm.lp[0][ss][h] + sm.lp[1][ss][h] + sm.lp[2][ss][h] + sm.lp[3][ss][h])
            * 0.17677669529663687f;
    lslot[((size_t)eb*CAPC + sc*64 + ss)*8 + h] = v;
  }
}

__device__ void dev_xattn(SMX& sm, int eb, int dc, int tid,
    const float* __restrict__ x, const float* __restrict__ lslot,
    const int* __restrict__ slot_token, float* __restrict__ xattn)
{
  int d0 = dc*64;
  {
    const float4* li = (const float4*)(lslot + (size_t)eb*CAPC*8);
    float4 v0 = li[tid*2], v1 = li[tid*2+1];
    sm.lS[tid][0]=v0.x; sm.lS[tid][1]=v0.y; sm.lS[tid][2]=v0.z; sm.lS[tid][3]=v0.w;
    sm.lS[tid][4]=v1.x; sm.lS[tid][5]=v1.y; sm.lS[tid][6]=v1.z; sm.lS[tid][7]=v1.w;
    sm.tokS[tid] = slot_token[eb*CAPC + tid];
  }
  __syncthreads();
  int lane = tid & 63, wave = tid >> 6;
#pragma unroll
  for (int r = 0; r < 2; ++r) {
    int hh = wave + r*4;
    float m = fmaxf(fmaxf(sm.lS[lane][hh], sm.lS[lane+64][hh]),
                    fmaxf(sm.lS[lane+128][hh], sm.lS[lane+192][hh]));
    m = fmaxf(m, __shfl_down(m,32)); m = fmaxf(m, __shfl_down(m,16));
    m = fmaxf(m, __shfl_down(m,8));  m = fmaxf(m, __shfl_down(m,4));
    m = fmaxf(m, __shfl_down(m,2));  m = fmaxf(m, __shfl_down(m,1));
    if (lane == 0) sm.red[hh] = m;
  }
  __syncthreads();
  float ex[8];
#pragma unroll
  for (int h = 0; h < 8; ++h) { ex[h] = expf(sm.lS[tid][h] - sm.red[h]); sm.lS[tid][h] = ex[h]; }
  __syncthreads();
#pragma unroll
  for (int r = 0; r < 2; ++r) {
    int hh = wave + r*4;
    float s = sm.lS[lane][hh] + sm.lS[lane+64][hh] + sm.lS[lane+128][hh] + sm.lS[lane+192][hh];
    s += __shfl_down(s,32); s += __shfl_down(s,16); s += __shfl_down(s,8);
    s += __shfl_down(s,4);  s += __shfl_down(s,2);  s += __shfl_down(s,1);
    if (lane == 0) sm.red[8+hh] = s;
  }
  __syncthreads();
#pragma unroll
  for (int h = 0; h < 8; ++h) sm.aS2[h][tid] = ex[h] / sm.red[8+h];
  __syncthreads();
  int d = tid & 63, sc = tid >> 6;
  const float* xb = x + d0 + d;
  float acc[8] = {0,0,0,0,0,0,0,0};
#pragma unroll 4
  for (int i = 0; i < 64; ++i) {
    int s = sc*64 + i;
    int tk = sm.tokS[s];
    int tkc = tk < 0 ? 0 : tk;
    float msk = tk < 0 ? 0.f : 1.f;
    float xv = xb[(size_t)tkc*DD] * msk;
#pragma unroll
    for (int h = 0; h < 8; ++h) acc[h] += sm.aS2[h][s] * xv;
  }
#pragma unroll
  for (int h = 0; h < 8; ++h) sm.part[sc][h][d] = acc[h];
  __syncthreads();
#pragma unroll
  for (int r = 0; r < 2; ++r) {
    int o = r*256 + tid;
    int h = o >> 6, d2 = o & 63;
    float v = sm.part[0][h][d2] + sm.part[1][h][d2] + sm.part[2][h][d2] + sm.part[3][h][d2];
    xattn[(size_t)eb*2048 + h*DD + d0 + d2] = v;
  }
}

__device__ void dev_o(SMO& sm, int e, int ch, int tid,
    const float* __restrict__ xattn, const float* __restrict__ Wkv,
    float* __restrict__ o_ws)
{
  int c0 = ch*32, h = ch;
  for (int i = tid; i < 2048; i += 256) {
    int b = i >> 8, d = i & 255;
    sm.xaS[b][d] = xattn[((size_t)(e*8 + b))*2048 + h*DD + d];
  }
  __syncthreads();
  int c = tid & 31, kc = tid >> 5;
  const float* wv = Wkv + (size_t)e*(DD*2*DD) + DD + c0 + c;
  float acc[8] = {0,0,0,0,0,0,0,0};
#pragma unroll
  for (int i = 0; i < 32; ++i) {
    int d = kc*32 + i;
    float w = wv[(size_t)d*(2*DD)];
#pragma unroll
    for (int b = 0; b < 8; ++b) acc[b] += w * sm.xaS[b][d];
  }
#pragma unroll
  for (int b = 0; b < 8; ++b) sm.op[kc][c][b] = acc[b];
  __syncthreads();
  int c2 = tid & 31, b2 = tid >> 5;
  float s = 0.f;
#pragma unroll
  for (int g = 0; g < 8; ++g) s += sm.op[g][c2][b2];
  o_ws[((size_t)(e*8 + b2))*DD + c0 + c2] = s;
}

__device__ void dev_gate(SMO& sm, int e, int ch, int tid,
    const float* __restrict__ o_ws, const float* __restrict__ Wp,
    const float* __restrict__ bp, float* __restrict__ gateW)
{
  int c0 = ch*32;
  for (int i = tid; i < 2048; i += 256) {
    int b = i >> 8, d = i & 255;
    sm.xaS[b][d] = o_ws[((size_t)(e*8 + b))*DD + d];
  }
  __syncthreads();
  int c = tid & 31, kc = tid >> 5;
  const float* wp = Wp + (size_t)e*DD*DD + c0 + c;
  float acc[8] = {0,0,0,0,0,0,0,0};
#pragma unroll
  for (int i = 0; i < 32; ++i) {
    int d = kc*32 + i;
    float w = wp[(size_t)d*DD];
#pragma unroll
    for (int b = 0; b < 8; ++b) acc[b] += w * sm.xaS[b][d];
  }
#pragma unroll
  for (int b = 0; b < 8; ++b) sm.op[kc][c][b] = acc[b];
  __syncthreads();
  int c2 = tid & 31, b2 = tid >> 5;
  float s = bp[e*DD + c0 + c2];
#pragma unroll
  for (int g = 0; g < 8; ++g) s += sm.op[g][c2][b2];
  gateW[((size_t)(e*8 + b2))*DD + c0 + c2] = 1.f / (1.f + expf(-s));
}

__device__ void dev_out(int idx0, int stride,
    const float* __restrict__ x, const float* __restrict__ g1a, const float* __restrict__ g2a,
    const int* __restrict__ idx1a, const int* __restrict__ idx2a,
    const float* __restrict__ gateW, float* __restrict__ out)
{
  for (int idx = idx0; idx < BN*DD/4; idx += stride) {
    int token = idx >> 6;
    int d4 = idx & 63;
    int b = token >> 11;
    float g1 = g1a[token], g2 = g2a[token];
    int e1 = idx1a[token], e2 = idx2a[token];
    float4 w1 = ((const float4*)(gateW + (size_t)(e1*BB+b)*DD))[d4];
    float4 w2 = ((const float4*)(gateW + (size_t)(e2*BB+b)*DD))[d4];
    float4 xv = ((const float4*)x)[idx];
    float4 o;
    o.x = xv.x*(g1*w1.x + g2*w2.x);
    o.y = xv.y*(g1*w1.y + g2*w2.y);
    o.z = xv.z*(g1*w1.z + g2*w2.z);
    o.w = xv.w*(g1*w1.w + g2*w2.w);
    ((float4*)out)[idx] = o;
  }
}

// ================================================================ cooperative mega-kernel
__global__ __launch_bounds__(256, 2) void mega_kernel(
    const float* __restrict__ x, const float* __restrict__ wg,
    const float* __restrict__ audio, const float* __restrict__ Wq,
    const float* __restrict__ Wkv, const float* __restrict__ Wp,
    const float* __restrict__ bp,
    int* __restrict__ idx1a, int* __restrict__ idx2a,
    float* __restrict__ g1a, float* __restrict__ g2a,
    float* __restrict__ raw_part, float* __restrict__ cnt_part,
    int* __restrict__ slot_token, float* __restrict__ rws,
    float* __restrict__ lslot, float* __restrict__ xattn,
    float* __restrict__ o_ws, float* __restrict__ gateW,
    float* __restrict__ out, float* __restrict__ out_loss)
{
  cg::grid_group grid = cg::this_grid();
  __shared__ SMU sm;
  int tid = threadIdx.x;
  int blk = blockIdx.x;

  if (blk < 256)      dev_gating(sm.g, blk, tid, x, wg, idx1a, idx2a, g1a, g2a, raw_part, cnt_part);
  else if (blk < 384) dev_qr(sm.q, blk - 256, tid, audio, Wq, Wkv, rws);
  __threadfence(); grid.sync();

  if (blk < 8) {
    dev_scan(sm.s, blk, tid, idx1a, idx2a, g1a, g2a, slot_token);
    if (blk == 0) dev_loss(sm.s, tid, raw_part, cnt_part, out_loss);
  }
  __threadfence(); grid.sync();

  dev_lslot(sm.l, blk >> 2, blk & 3, tid, x, rws, slot_token, lslot);
  __threadfence(); grid.sync();

  dev_xattn(sm.xa, blk >> 2, blk & 3, tid, x, lslot, slot_token, xattn);
  __threadfence(); grid.sync();

  if (blk < 128) dev_o(sm.og, blk >> 3, blk & 7, tid, xattn, Wkv, o_ws);
  __threadfence(); grid.sync();

  if (blk < 128) dev_gate(sm.og, blk >> 3, blk & 7, tid, o_ws, Wp, bp, gateW);
  __threadfence(); grid.sync();

  dev_out(blk*256 + tid, GRID*256, x, g1a, g2a, idx1a, idx2a, gateW, out);
}

// ================================================================ fallback kernels (R5 pipeline)
__global__ __launch_bounds__(256) void k_gq(
    const float* __restrict__ x, const float* __restrict__ wg,
    const float* __restrict__ audio, const float* __restrict__ Wq,
    const float* __restrict__ Wkv,
    int* __restrict__ idx1a, int* __restrict__ idx2a,
    float* __restrict__ g1a, float* __restrict__ g2a,
    float* __restrict__ raw_part, float* __restrict__ cnt_part,
    float* __restrict__ rws)
{
  __shared__ union { SMG g; SMQ q; } sm;
  if (blockIdx.x < 256)
    dev_gating(sm.g, blockIdx.x, threadIdx.x, x, wg, idx1a, idx2a, g1a, g2a, raw_part, cnt_part);
  else
    dev_qr(sm.q, blockIdx.x - 256, threadIdx.x, audio, Wq, Wkv, rws);
}

__global__ __launch_bounds__(256) void k_scan(
    const int* __restrict__ idx1a, const int* __restrict__ idx2a,
    float* __restrict__ g1a, float* __restrict__ g2a, int* __restrict__ slot_token,
    const float* __restrict__ raw_part, const float* __restrict__ cnt_part,
    float* __restrict__ out_loss)
{
  __shared__ SMS sm;
  dev_scan(sm, blockIdx.x, threadIdx.x, idx1a, idx2a, g1a, g2a, slot_token);
  if (blockIdx.x == 0) dev_loss(sm, threadIdx.x, raw_part, cnt_part, out_loss);
}

__global__ __launch_bounds__(256) void k_lslot(
    const float* __restrict__ x, const float* __restrict__ rws,
    const int* __restrict__ slot_token, float* __restrict__ lslot)
{
  __shared__ SML sm;
  dev_lslot(sm, blockIdx.x >> 2, blockIdx.x & 3, threadIdx.x, x, rws, slot_token, lslot);
}

__global__ __launch_bounds__(256) void k_xattn(
    const float* __restrict__ x, const float* __restrict__ lslot,
    const int* __restrict__ slot_token, float* __restrict__ xattn)
{
  __shared__ SMX sm;
  dev_xattn(sm, blockIdx.x >> 2, blockIdx.x & 3, threadIdx.x, x, lslot, slot_token, xattn);
}

__global__ __launch_bounds__(256) void k_o(
    const float* __restrict__ xattn, const float* __restrict__ Wkv,
    float* __restrict__ o_ws)
{
  __shared__ SMO sm;
  dev_o(sm, blockIdx.x >> 3, blockIdx.x & 7, threadIdx.x, xattn, Wkv, o_ws);
}

__global__ __launch_bounds__(256) void k_gate(
    const float* __restrict__ o_ws, const float* __restrict__ Wp,
    const float* __restrict__ bp, float* __restrict__ gateW)
{
  __shared__ SMO sm;
  dev_gate(sm, blockIdx.x >> 3, blockIdx.x & 7, threadIdx.x, o_ws, Wp, bp, gateW);
}

__global__ __launch_bounds__(256) void k_out(
    const float* __restrict__ x, const float* __restrict__ g1a, const float* __restrict__ g2a,
    const int* __restrict__ idx1a, const int* __restrict__ idx2a,
    const float* __restrict__ gateW, float* __restrict__ out)
{
  int idx = blockIdx.x*256 + threadIdx.x;
  dev_out(idx, BN*DD/4, x, g1a, g2a, idx1a, idx2a, gateW, out);
}

// ================================================================ launcher
extern "C" void kernel_launch(void* const* d_in, const int* in_sizes, int n_in,
                              void* d_out, int out_size, void* d_ws, size_t ws_size,
                              hipStream_t stream)
{
  const float* x     = (const float*)d_in[0];
  const float* audio = (const float*)d_in[1];
  const float* wg    = (const float*)d_in[2];
  const float* Wq    = (const float*)d_in[3];
  const float* Wkv   = (const float*)d_in[4];
  const float* Wp    = (const float*)d_in[5];
  const float* bp    = (const float*)d_in[6];
  float* out = (float*)d_out;

  float* raw_part = (float*)d_ws;                      // 256*16
  float* cnt_part = raw_part + 256*16;                 // 256*16
  int*   idx1a   = (int*)(cnt_part + 256*16);          // BN
  int*   idx2a   = idx1a + BN;                         // BN
  float* g1a     = (float*)(idx2a + BN);               // BN
  float* g2a     = g1a + BN;                           // BN
  int*   slot_token = (int*)(g2a + BN);                // EB*CAP
  float* rws     = (float*)(slot_token + EB*CAPC);     // EB*2048
  float* lslot   = rws + (size_t)EB*2048;              // EB*CAP*8
  float* xattn   = lslot + (size_t)EB*CAPC*8;          // EB*2048
  float* o_ws    = xattn + (size_t)EB*2048;            // EB*256
  float* gateW   = o_ws + (size_t)EB*DD;               // EB*256
  float* out_loss = out + (size_t)out_size - 1;

  void* args[] = {
    (void*)&x, (void*)&wg, (void*)&audio, (void*)&Wq, (void*)&Wkv,
    (void*)&Wp, (void*)&bp,
    (void*)&idx1a, (void*)&idx2a, (void*)&g1a, (void*)&g2a,
    (void*)&raw_part, (void*)&cnt_part, (void*)&slot_token, (void*)&rws,
    (void*)&lslot, (void*)&xattn, (void*)&o_ws, (void*)&gateW,
    (void*)&out, (void*)&out_loss
  };
  hipError_t st = hipLaunchCooperativeKernel((void*)mega_kernel, dim3(GRID), dim3(256),
                                             args, 0, stream);
  if (st != hipSuccess) {
    (void)hipGetLastError();   // clear sticky error, use proven 7-kernel path
    k_gq   <<<384, 256, 0, stream>>>(x, wg, audio, Wq, Wkv,
                                     idx1a, idx2a, g1a, g2a, raw_part, cnt_part, rws);
    k_scan <<<BB, 256, 0, stream>>>(idx1a, idx2a, g1a, g2a, slot_token,
                                    raw_part, cnt_part, out_loss);
    k_lslot<<<EB*4, 256, 0, stream>>>(x, rws, slot_token, lslot);
    k_xattn<<<EB*4, 256, 0, stream>>>(x, lslot, slot_token, xattn);
    k_o    <<<EB, 256, 0, stream>>>(xattn, Wkv, o_ws);
    k_gate <<<EB, 256, 0, stream>>>(o_ws, Wp, bp, gateW);
    k_out  <<<(BN*DD/4)/256, 256, 0, stream>>>(x, g1a, g2a, idx1a, idx2a, gateW, out);
  }
}

// Round 8
// 162.857 us; speedup vs baseline: 4.4474x; 4.4474x over previous
//
#include <hip/hip_runtime.h>
#include <cstdint>
#include <cstddef>

#define BB 8
#define NN 2048
#define DD 256
#define EE 16
#define HH 8
#define CAPC 256
#define BN (BB*NN)   // 16384
#define EB (EE*BB)   // 128

// ---------------- shared-memory phase structs ----------------
struct SMG { float wgS[DD*EE]; float lgp[4][64][17]; };                        // 33.8 KB
struct SMQ { float aS[DD][8]; float qpart[8][32][9]; float qS[32][8]; };       // 18.2 KB
struct SMS { unsigned long long m1s[16][32], m2s[16][32];
             int wp1[16][32], wp2[16][32], mcnt[16]; float r4[4]; };           // 12.3 KB
struct SML { float rS[DD][8]; float lp[4][64][9]; int tokS[64]; };             // 17.5 KB
struct SMX { float lS[CAPC][9]; float aS2[HH][CAPC]; float part[4][HH][64];
             int tokS[CAPC]; float red[16]; };                                 // 26.4 KB
struct SMO { float xaS[8][DD]; float op[8][32][9]; };                          // 17.2 KB

// ================================================================ phase device functions
// (all correctness-proven end-to-end in R7's run)
__device__ void dev_gating(SMG& sm, int blk, int tid,
    const float* __restrict__ x, const float* __restrict__ wg,
    int* __restrict__ idx1a, int* __restrict__ idx2a,
    float* __restrict__ g1a, float* __restrict__ g2a,
    float* __restrict__ raw_part, float* __restrict__ cnt_part)
{
  for (int t = tid; t < DD*EE; t += 256) sm.wgS[t] = wg[t];
  __syncthreads();
  int tk = tid & 63, kc = tid >> 6;
  int token0 = blk * 64;
  int token = token0 + tk;
  const float4* xr = (const float4*)(x + (size_t)token*DD + kc*64);
  const float4* wg4 = (const float4*)sm.wgS;
  float lg[16];
#pragma unroll
  for (int e = 0; e < 16; ++e) lg[e] = 0.f;
#pragma unroll
  for (int d4 = 0; d4 < 16; ++d4) {
    float4 xv = xr[d4];
    float xav[4] = {xv.x, xv.y, xv.z, xv.w};
#pragma unroll
    for (int dd = 0; dd < 4; ++dd) {
      int d = kc*64 + d4*4 + dd;
      float xc = xav[dd];
#pragma unroll
      for (int j = 0; j < 4; ++j) {
        float4 w = wg4[d*4 + j];
        lg[4*j+0] += xc*w.x; lg[4*j+1] += xc*w.y;
        lg[4*j+2] += xc*w.z; lg[4*j+3] += xc*w.w;
      }
    }
  }
#pragma unroll
  for (int e = 0; e < 16; ++e) sm.lgp[kc][tk][e] = lg[e];
  __syncthreads();
  if (tid < 64) {
    int lane = tid;
    float l[16];
#pragma unroll
    for (int e = 0; e < 16; ++e)
      l[e] = sm.lgp[0][lane][e] + sm.lgp[1][lane][e]
           + sm.lgp[2][lane][e] + sm.lgp[3][lane][e];
    float mx = l[0];
#pragma unroll
    for (int e = 1; e < 16; ++e) mx = fmaxf(mx, l[e]);
    float p[16]; float s = 0.f;
#pragma unroll
    for (int e = 0; e < 16; ++e) { p[e] = expf(l[e] - mx); s += p[e]; }
    int i1 = 0; float b1 = p[0];
#pragma unroll
    for (int e = 1; e < 16; ++e) { if (p[e] > b1) { b1 = p[e]; i1 = e; } }
    float b2 = (i1 == 0) ? 0.f : p[0]; int i2 = 0;
#pragma unroll
    for (int e = 1; e < 16; ++e) { float v = (e == i1) ? 0.f : p[e]; if (v > b2) { b2 = v; i2 = e; } }
    float inv = 1.f / s;
    float g1 = b1*inv, g2 = b2*inv;
    float den = g1 + g2 + 1e-9f;
    g1 /= den; g2 /= den;
    int tok = token0 + lane;
    idx1a[tok] = i1; idx2a[tok] = i2;
    g1a[tok] = g1;   g2a[tok] = g2;
#pragma unroll
    for (int e = 0; e < 16; ++e) {
      float v = p[e] * inv;
      v += __shfl_down(v, 32); v += __shfl_down(v, 16);
      v += __shfl_down(v, 8);  v += __shfl_down(v, 4);
      v += __shfl_down(v, 2);  v += __shfl_down(v, 1);
      unsigned long long mb = __ballot(i1 == e);
      if (lane == 0) {
        raw_part[blk*16 + e] = v;
        cnt_part[blk*16 + e] = (float)__popcll(mb);
      }
    }
  }
}

__device__ void dev_qr(SMQ& sm, int eh, int tid,
    const float* __restrict__ audio, const float* __restrict__ Wq,
    const float* __restrict__ Wkv, float* __restrict__ rws)
{
  int e = eh >> 3, h = eh & 7;
  for (int i = tid; i < 2048; i += 256) { int b = i >> 8, k = i & 255; sm.aS[k][b] = audio[b*DD + k]; }
  __syncthreads();
  int j = tid & 31, kg = tid >> 5;
  const float* wq = Wq + (size_t)e*DD*DD + h*32 + j;
  float acc[8] = {0,0,0,0,0,0,0,0};
#pragma unroll
  for (int i = 0; i < 32; ++i) {
    int k = kg*32 + i;
    float w = wq[(size_t)k*DD];
    float4 a0 = *(const float4*)&sm.aS[k][0];
    float4 a1 = *(const float4*)&sm.aS[k][4];
    acc[0]+=w*a0.x; acc[1]+=w*a0.y; acc[2]+=w*a0.z; acc[3]+=w*a0.w;
    acc[4]+=w*a1.x; acc[5]+=w*a1.y; acc[6]+=w*a1.z; acc[7]+=w*a1.w;
  }
#pragma unroll
  for (int b = 0; b < 8; ++b) sm.qpart[kg][j][b] = acc[b];
  __syncthreads();
  {
    int jj = tid >> 3, b = tid & 7;
    float s = 0.f;
#pragma unroll
    for (int g = 0; g < 8; ++g) s += sm.qpart[g][jj][b];
    sm.qS[jj][b] = s;
  }
  __syncthreads();
  // r[b][d] = sum_j Wk[e][d][h*32+j] * q[j][b]; thread = d, Wk row streamed from global
  int d = tid;
  const float4* wk4 = (const float4*)(Wkv + (size_t)e*(DD*2*DD) + (size_t)d*(2*DD) + h*32);
  float racc[8] = {0,0,0,0,0,0,0,0};
#pragma unroll
  for (int j4 = 0; j4 < 8; ++j4) {
    float4 w4 = wk4[j4];
    float wa[4] = {w4.x, w4.y, w4.z, w4.w};
#pragma unroll
    for (int c = 0; c < 4; ++c) {
      int jj = j4*4 + c;
      float w = wa[c];
      float4 q0 = *(const float4*)&sm.qS[jj][0];
      float4 q1 = *(const float4*)&sm.qS[jj][4];
      racc[0]+=w*q0.x; racc[1]+=w*q0.y; racc[2]+=w*q0.z; racc[3]+=w*q0.w;
      racc[4]+=w*q1.x; racc[5]+=w*q1.y; racc[6]+=w*q1.z; racc[7]+=w*q1.w;
    }
  }
#pragma unroll
  for (int b = 0; b < 8; ++b)
    rws[((size_t)(e*8 + b))*2048 + d*8 + h] = racc[b];
}

__device__ void dev_scan(SMS& sm, int b, int tid,
    const int* __restrict__ idx1a, const int* __restrict__ idx2a,
    float* __restrict__ g1a, float* __restrict__ g2a, int* __restrict__ slot_token)
{
  int wave = tid >> 6, lane = tid & 63;
  for (int i = tid; i < 16*CAPC; i += 256) {
    int e = i >> 8, s = i & 255;
    slot_token[(e*BB + b)*CAPC + s] = -1;
  }
  for (int w = wave; w < 32; w += 4) {
    int token = b*NN + w*64 + lane;
    int i1 = idx1a[token], i2 = idx2a[token];
#pragma unroll
    for (int e = 0; e < 16; ++e) {
      unsigned long long ma = __ballot(i1 == e);
      unsigned long long mb = __ballot(i2 == e);
      if (lane == 0) { sm.m1s[e][w] = ma; sm.m2s[e][w] = mb; }
    }
  }
  __syncthreads();
  if (tid < 16) {
    int run = 0;
    for (int w = 0; w < 32; ++w) { sm.wp1[tid][w] = run; run += (int)__popcll(sm.m1s[tid][w]); }
    sm.mcnt[tid] = run < CAPC ? run : CAPC;
  } else if (tid < 32) {
    int e2 = tid - 16; int run = 0;
    for (int w = 0; w < 32; ++w) { sm.wp2[e2][w] = run; run += (int)__popcll(sm.m2s[e2][w]); }
  }
  __syncthreads();
  for (int w = wave; w < 32; w += 4) {
    int token = b*NN + w*64 + lane;
    int i1 = idx1a[token], i2 = idx2a[token];
    unsigned long long lt = (1ull << lane) - 1ull;
    int pos1 = sm.wp1[i1][w] + (int)__popcll(sm.m1s[i1][w] & lt);
    float g1 = g1a[token];
    bool k1 = pos1 < CAPC;
    g1a[token] = k1 ? g1 : 0.f;
    if (k1) slot_token[(i1*BB + b)*CAPC + pos1] = token;
    int pos2 = sm.mcnt[i2] + sm.wp2[i2][w] + (int)__popcll(sm.m2s[i2][w] & lt);
    float g2 = g2a[token];
    bool k2 = pos2 < CAPC;
    g2a[token] = k2 ? g2 : 0.f;
    if (k2 && g2 > 0.f) slot_token[(i2*BB + b)*CAPC + pos2] = token;
  }
}

__device__ void dev_loss(SMS& sm, int tid,
    const float* __restrict__ raw_part, const float* __restrict__ cnt_part,
    float* __restrict__ out_loss)
{
  float v = 0.f;
  if (tid < 128) {
    int bb = tid >> 4, e = tid & 15;
    float rs = 0.f, cs = 0.f;
#pragma unroll 4
    for (int k = 0; k < 32; ++k) {
      rs += raw_part[(bb*32 + k)*16 + e];
      cs += cnt_part[(bb*32 + k)*16 + e];
    }
    v = (rs * (1.f/(float)NN)) * (cs * (1.f/(float)NN));
  }
  v += __shfl_down(v, 32); v += __shfl_down(v, 16); v += __shfl_down(v, 8);
  v += __shfl_down(v, 4);  v += __shfl_down(v, 2);  v += __shfl_down(v, 1);
  if ((tid & 63) == 0) sm.r4[tid >> 6] = v;
  __syncthreads();
  if (tid == 0)
    out_loss[0] = (sm.r4[0]+sm.r4[1]+sm.r4[2]+sm.r4[3])
                * ((float)(EE*EE) / (float)(BB*EE)) * 0.01f;
}

__device__ void dev_lslot(SML& sm, int eb, int sc, int tid,
    const float* __restrict__ x, const float* __restrict__ rws,
    const int* __restrict__ slot_token, float* __restrict__ lslot)
{
  {
    const float4* rin = (const float4*)(rws + (size_t)eb*2048);
    float4* rS4 = (float4*)sm.rS;
    rS4[tid] = rin[tid]; rS4[tid+256] = rin[tid+256];
  }
  if (tid < 64) sm.tokS[tid] = slot_token[eb*CAPC + sc*64 + tid];
  __syncthreads();
  int s = tid >> 2, q = tid & 3;
  int token = sm.tokS[s];
  float l[8] = {0,0,0,0,0,0,0,0};
  if (token >= 0) {
    const float4* xr = (const float4*)(x + (size_t)token*DD + q*64);
#pragma unroll
    for (int i = 0; i < 16; ++i) {
      float4 xv = xr[i];
      float xav[4] = {xv.x, xv.y, xv.z, xv.w};
#pragma unroll
      for (int dd = 0; dd < 4; ++dd) {
        int d = q*64 + i*4 + dd;
        float4 r0 = *(const float4*)&sm.rS[d][0];
        float4 r1 = *(const float4*)&sm.rS[d][4];
        float xc = xav[dd];
        l[0]+=xc*r0.x; l[1]+=xc*r0.y; l[2]+=xc*r0.z; l[3]+=xc*r0.w;
        l[4]+=xc*r1.x; l[5]+=xc*r1.y; l[6]+=xc*r1.z; l[7]+=xc*r1.w;
      }
    }
  }
#pragma unroll
  for (int h = 0; h < 8; ++h) sm.lp[q][s][h] = l[h];
  __syncthreads();
#pragma unroll
  for (int r = 0; r < 2; ++r) {
    int o = tid*2 + r;
    int ss = o >> 3, h = o & 7;
    float v = (sm.lp[0][ss][h] + sm.lp[1][ss][h] + sm.lp[2][ss][h] + sm.lp[3][ss][h])
            * 0.17677669529663687f;
    lslot[((size_t)eb*CAPC + sc*64 + ss)*8 + h] = v;
  }
}

__device__ void dev_xattn(SMX& sm, int eb, int dc, int tid,
    const float* __restrict__ x, const float* __restrict__ lslot,
    const int* __restrict__ slot_token, float* __restrict__ xattn)
{
  int d0 = dc*64;
  {
    const float4* li = (const float4*)(lslot + (size_t)eb*CAPC*8);
    float4 v0 = li[tid*2], v1 = li[tid*2+1];
    sm.lS[tid][0]=v0.x; sm.lS[tid][1]=v0.y; sm.lS[tid][2]=v0.z; sm.lS[tid][3]=v0.w;
    sm.lS[tid][4]=v1.x; sm.lS[tid][5]=v1.y; sm.lS[tid][6]=v1.z; sm.lS[tid][7]=v1.w;
    sm.tokS[tid] = slot_token[eb*CAPC + tid];
  }
  __syncthreads();
  int lane = tid & 63, wave = tid >> 6;
#pragma unroll
  for (int r = 0; r < 2; ++r) {
    int hh = wave + r*4;
    float m = fmaxf(fmaxf(sm.lS[lane][hh], sm.lS[lane+64][hh]),
                    fmaxf(sm.lS[lane+128][hh], sm.lS[lane+192][hh]));
    m = fmaxf(m, __shfl_down(m,32)); m = fmaxf(m, __shfl_down(m,16));
    m = fmaxf(m, __shfl_down(m,8));  m = fmaxf(m, __shfl_down(m,4));
    m = fmaxf(m, __shfl_down(m,2));  m = fmaxf(m, __shfl_down(m,1));
    if (lane == 0) sm.red[hh] = m;
  }
  __syncthreads();
  float ex[8];
#pragma unroll
  for (int h = 0; h < 8; ++h) { ex[h] = expf(sm.lS[tid][h] - sm.red[h]); sm.lS[tid][h] = ex[h]; }
  __syncthreads();
#pragma unroll
  for (int r = 0; r < 2; ++r) {
    int hh = wave + r*4;
    float s = sm.lS[lane][hh] + sm.lS[lane+64][hh] + sm.lS[lane+128][hh] + sm.lS[lane+192][hh];
    s += __shfl_down(s,32); s += __shfl_down(s,16); s += __shfl_down(s,8);
    s += __shfl_down(s,4);  s += __shfl_down(s,2);  s += __shfl_down(s,1);
    if (lane == 0) sm.red[8+hh] = s;
  }
  __syncthreads();
#pragma unroll
  for (int h = 0; h < 8; ++h) sm.aS2[h][tid] = ex[h] / sm.red[8+h];
  __syncthreads();
  int d = tid & 63, sc = tid >> 6;
  const float* xb = x + d0 + d;
  float acc[8] = {0,0,0,0,0,0,0,0};
#pragma unroll 4
  for (int i = 0; i < 64; ++i) {
    int s = sc*64 + i;
    int tk = sm.tokS[s];
    int tkc = tk < 0 ? 0 : tk;
    float msk = tk < 0 ? 0.f : 1.f;
    float xv = xb[(size_t)tkc*DD] * msk;
#pragma unroll
    for (int h = 0; h < 8; ++h) acc[h] += sm.aS2[h][s] * xv;
  }
#pragma unroll
  for (int h = 0; h < 8; ++h) sm.part[sc][h][d] = acc[h];
  __syncthreads();
#pragma unroll
  for (int r = 0; r < 2; ++r) {
    int o = r*256 + tid;
    int h = o >> 6, d2 = o & 63;
    float v = sm.part[0][h][d2] + sm.part[1][h][d2] + sm.part[2][h][d2] + sm.part[3][h][d2];
    xattn[(size_t)eb*2048 + h*DD + d0 + d2] = v;
  }
}

__device__ void dev_o(SMO& sm, int e, int ch, int tid,
    const float* __restrict__ xattn, const float* __restrict__ Wkv,
    float* __restrict__ o_ws)
{
  int c0 = ch*32, h = ch;
  for (int i = tid; i < 2048; i += 256) {
    int b = i >> 8, d = i & 255;
    sm.xaS[b][d] = xattn[((size_t)(e*8 + b))*2048 + h*DD + d];
  }
  __syncthreads();
  int c = tid & 31, kc = tid >> 5;
  const float* wv = Wkv + (size_t)e*(DD*2*DD) + DD + c0 + c;
  float acc[8] = {0,0,0,0,0,0,0,0};
#pragma unroll
  for (int i = 0; i < 32; ++i) {
    int d = kc*32 + i;
    float w = wv[(size_t)d*(2*DD)];
#pragma unroll
    for (int b = 0; b < 8; ++b) acc[b] += w * sm.xaS[b][d];
  }
#pragma unroll
  for (int b = 0; b < 8; ++b) sm.op[kc][c][b] = acc[b];
  __syncthreads();
  int c2 = tid & 31, b2 = tid >> 5;
  float s = 0.f;
#pragma unroll
  for (int g = 0; g < 8; ++g) s += sm.op[g][c2][b2];
  o_ws[((size_t)(e*8 + b2))*DD + c0 + c2] = s;
}

__device__ void dev_gate(SMO& sm, int e, int ch, int tid,
    const float* __restrict__ o_ws, const float* __restrict__ Wp,
    const float* __restrict__ bp, float* __restrict__ gateW)
{
  int c0 = ch*32;
  for (int i = tid; i < 2048; i += 256) {
    int b = i >> 8, d = i & 255;
    sm.xaS[b][d] = o_ws[((size_t)(e*8 + b))*DD + d];
  }
  __syncthreads();
  int c = tid & 31, kc = tid >> 5;
  const float* wp = Wp + (size_t)e*DD*DD + c0 + c;
  float acc[8] = {0,0,0,0,0,0,0,0};
#pragma unroll
  for (int i = 0; i < 32; ++i) {
    int d = kc*32 + i;
    float w = wp[(size_t)d*DD];
#pragma unroll
    for (int b = 0; b < 8; ++b) acc[b] += w * sm.xaS[b][d];
  }
#pragma unroll
  for (int b = 0; b < 8; ++b) sm.op[kc][c][b] = acc[b];
  __syncthreads();
  int c2 = tid & 31, b2 = tid >> 5;
  float s = bp[e*DD + c0 + c2];
#pragma unroll
  for (int g = 0; g < 8; ++g) s += sm.op[g][c2][b2];
  gateW[((size_t)(e*8 + b2))*DD + c0 + c2] = 1.f / (1.f + expf(-s));
}

__device__ void dev_out(int idx0, int stride,
    const float* __restrict__ x, const float* __restrict__ g1a, const float* __restrict__ g2a,
    const int* __restrict__ idx1a, const int* __restrict__ idx2a,
    const float* __restrict__ gateW, float* __restrict__ out)
{
  for (int idx = idx0; idx < BN*DD/4; idx += stride) {
    int token = idx >> 6;
    int d4 = idx & 63;
    int b = token >> 11;
    float g1 = g1a[token], g2 = g2a[token];
    int e1 = idx1a[token], e2 = idx2a[token];
    float4 w1 = ((const float4*)(gateW + (size_t)(e1*BB+b)*DD))[d4];
    float4 w2 = ((const float4*)(gateW + (size_t)(e2*BB+b)*DD))[d4];
    float4 xv = ((const float4*)x)[idx];
    float4 o;
    o.x = xv.x*(g1*w1.x + g2*w2.x);
    o.y = xv.y*(g1*w1.y + g2*w2.y);
    o.z = xv.z*(g1*w1.z + g2*w2.z);
    o.w = xv.w*(g1*w1.w + g2*w2.w);
    ((float4*)out)[idx] = o;
  }
}

// ================================================================ kernels (7-launch pipeline)
__global__ __launch_bounds__(256) void k_gq(
    const float* __restrict__ x, const float* __restrict__ wg,
    const float* __restrict__ audio, const float* __restrict__ Wq,
    const float* __restrict__ Wkv,
    int* __restrict__ idx1a, int* __restrict__ idx2a,
    float* __restrict__ g1a, float* __restrict__ g2a,
    float* __restrict__ raw_part, float* __restrict__ cnt_part,
    float* __restrict__ rws)
{
  __shared__ union { SMG g; SMQ q; } sm;   // 33.8 KB -> 4 blocks/CU
  if (blockIdx.x < 256)
    dev_gating(sm.g, blockIdx.x, threadIdx.x, x, wg, idx1a, idx2a, g1a, g2a, raw_part, cnt_part);
  else
    dev_qr(sm.q, blockIdx.x - 256, threadIdx.x, audio, Wq, Wkv, rws);
}

__global__ __launch_bounds__(256) void k_scan(
    const int* __restrict__ idx1a, const int* __restrict__ idx2a,
    float* __restrict__ g1a, float* __restrict__ g2a, int* __restrict__ slot_token,
    const float* __restrict__ raw_part, const float* __restrict__ cnt_part,
    float* __restrict__ out_loss)
{
  __shared__ SMS sm;
  dev_scan(sm, blockIdx.x, threadIdx.x, idx1a, idx2a, g1a, g2a, slot_token);
  if (blockIdx.x == 0) dev_loss(sm, threadIdx.x, raw_part, cnt_part, out_loss);
}

__global__ __launch_bounds__(256) void k_lslot(
    const float* __restrict__ x, const float* __restrict__ rws,
    const int* __restrict__ slot_token, float* __restrict__ lslot)
{
  __shared__ SML sm;
  dev_lslot(sm, blockIdx.x >> 2, blockIdx.x & 3, threadIdx.x, x, rws, slot_token, lslot);
}

__global__ __launch_bounds__(256) void k_xattn(
    const float* __restrict__ x, const float* __restrict__ lslot,
    const int* __restrict__ slot_token, float* __restrict__ xattn)
{
  __shared__ SMX sm;
  dev_xattn(sm, blockIdx.x >> 2, blockIdx.x & 3, threadIdx.x, x, lslot, slot_token, xattn);
}

__global__ __launch_bounds__(256) void k_o(
    const float* __restrict__ xattn, const float* __restrict__ Wkv,
    float* __restrict__ o_ws)
{
  __shared__ SMO sm;
  dev_o(sm, blockIdx.x >> 3, blockIdx.x & 7, threadIdx.x, xattn, Wkv, o_ws);
}

__global__ __launch_bounds__(256) void k_gate(
    const float* __restrict__ o_ws, const float* __restrict__ Wp,
    const float* __restrict__ bp, float* __restrict__ gateW)
{
  __shared__ SMO sm;
  dev_gate(sm, blockIdx.x >> 3, blockIdx.x & 7, threadIdx.x, o_ws, Wp, bp, gateW);
}

__global__ __launch_bounds__(256) void k_out(
    const float* __restrict__ x, const float* __restrict__ g1a, const float* __restrict__ g2a,
    const int* __restrict__ idx1a, const int* __restrict__ idx2a,
    const float* __restrict__ gateW, float* __restrict__ out)
{
  int idx = blockIdx.x*256 + threadIdx.x;
  dev_out(idx, BN*DD/4, x, g1a, g2a, idx1a, idx2a, gateW, out);
}

// ================================================================ launcher
extern "C" void kernel_launch(void* const* d_in, const int* in_sizes, int n_in,
                              void* d_out, int out_size, void* d_ws, size_t ws_size,
                              hipStream_t stream)
{
  const float* x     = (const float*)d_in[0];
  const float* audio = (const float*)d_in[1];
  const float* wg    = (const float*)d_in[2];
  const float* Wq    = (const float*)d_in[3];
  const float* Wkv   = (const float*)d_in[4];
  const float* Wp    = (const float*)d_in[5];
  const float* bp    = (const float*)d_in[6];
  float* out = (float*)d_out;

  float* raw_part = (float*)d_ws;                      // 256*16
  float* cnt_part = raw_part + 256*16;                 // 256*16
  int*   idx1a   = (int*)(cnt_part + 256*16);          // BN
  int*   idx2a   = idx1a + BN;                         // BN
  float* g1a     = (float*)(idx2a + BN);               // BN (scan truncates in place)
  float* g2a     = g1a + BN;                           // BN
  int*   slot_token = (int*)(g2a + BN);                // EB*CAP
  float* rws     = (float*)(slot_token + EB*CAPC);     // EB*2048
  float* lslot   = rws + (size_t)EB*2048;              // EB*CAP*8
  float* xattn   = lslot + (size_t)EB*CAPC*8;          // EB*2048
  float* o_ws    = xattn + (size_t)EB*2048;            // EB*256
  float* gateW   = o_ws + (size_t)EB*DD;               // EB*256
  float* out_loss = out + (size_t)out_size - 1;

  k_gq   <<<384, 256, 0, stream>>>(x, wg, audio, Wq, Wkv,
                                   idx1a, idx2a, g1a, g2a, raw_part, cnt_part, rws);
  k_scan <<<BB, 256, 0, stream>>>(idx1a, idx2a, g1a, g2a, slot_token,
                                  raw_part, cnt_part, out_loss);
  k_lslot<<<EB*4, 256, 0, stream>>>(x, rws, slot_token, lslot);
  k_xattn<<<EB*4, 256, 0, stream>>>(x, lslot, slot_token, xattn);
  k_o    <<<EB, 256, 0, stream>>>(xattn, Wkv, o_ws);
  k_gate <<<EB, 256, 0, stream>>>(o_ws, Wp, bp, gateW);
  k_out  <<<(BN*DD/4)/256, 256, 0, stream>>>(x, g1a, g2a, idx1a, idx2a, gateW, out);
}